// Round 2
// baseline (461.714 us; speedup 1.0000x reference)
//
#include <hip/hip_runtime.h>

#define Bq 128
#define Sq 512
#define Cq 37
#define Dq 768
#define VST 40   // vhist row stride in floats; bp row stride uses Sq

static __device__ __forceinline__ float frl(float v, int lane) {
  return __int_as_float(__builtin_amdgcn_readlane(__float_as_int(v), lane));
}
static __device__ __forceinline__ float ffl(float v) {
  return __int_as_float(__builtin_amdgcn_readfirstlane(__float_as_int(v)));
}

// ---------------- Kernel 1: emissions = x @ W + b ----------------
__global__ __launch_bounds__(256) void emis_kernel(
    const float* __restrict__ x, const float* __restrict__ W,
    const float* __restrict__ bias, float* __restrict__ em)
{
  int token = blockIdx.x * 256 + threadIdx.x;           // 0..65535
  const float* xr = x + (size_t)token * Dq;
  float acc[Cq];
#pragma unroll
  for (int c = 0; c < Cq; ++c) acc[c] = bias[c];
  for (int d = 0; d < Dq; d += 4) {
    float4 xv = *(const float4*)(xr + d);
#pragma unroll
    for (int c = 0; c < Cq; ++c) {
      acc[c] += xv.x * W[(d + 0) * Cq + c];
      acc[c] += xv.y * W[(d + 1) * Cq + c];
      acc[c] += xv.z * W[(d + 2) * Cq + c];
      acc[c] += xv.w * W[(d + 3) * Cq + c];
    }
  }
  float* o = em + (size_t)token * Cq;
#pragma unroll
  for (int c = 0; c < Cq; ++c) o[c] = acc[c];
}

// ---------------- Kernel 2: serial CRF (forward LSE, viterbi values, gold score) ----------------
__global__ __launch_bounds__(256) void crf_serial_kernel(
    const float* __restrict__ em, const float* __restrict__ startv,
    const float* __restrict__ endv, const float* __restrict__ trans,
    const int* __restrict__ labels, const unsigned char* __restrict__ maskb,
    float* __restrict__ vhist, float* __restrict__ llp,
    int* __restrict__ lenp, int* __restrict__ lastp)
{
  int b = blockIdx.x;
  int tid = threadIdx.x, wid = tid >> 6, lane = tid & 63;
  int cl = lane < Cq ? lane : Cq - 1;
  __shared__ float s_score, s_logZ;

  // mask element-size detect: bool(u8) layout has byte1==1 (len>=16), int32 has 0
  int esz4 = (maskb[1] == 0) ? 1 : 0;
  int len = 0;
#pragma unroll
  for (int k = 0; k < 8; ++k) {
    size_t t = (size_t)lane + (size_t)k * 64;
    unsigned char mb = esz4 ? maskb[((size_t)b * Sq + t) * 4] : maskb[(size_t)b * Sq + t];
    len += (mb != 0);
  }
#pragma unroll
  for (int off = 32; off; off >>= 1) len += __shfl_xor(len, off);

  const float* emb = em + (size_t)b * Sq * Cq;
  const float L2E = 1.4426950408889634f, LN2 = 0.6931471805599453f;

  if (wid == 0) {
    // ---- forward algorithm (log partition) ----
    float Ecol[Cq];
#pragma unroll
    for (int p = 0; p < Cq; ++p) Ecol[p] = expf(trans[p * Cq + cl]);
    float alpha = (lane < Cq) ? (startv[cl] + emb[cl]) : -3.0e38f;
    float emA = emb[Cq + cl];
    float emB = emb[(size_t)(2 < len ? 2 : len - 1) * Cq + cl];
    for (int t = 1; t < len; ++t) {
      float em_cur = emA; emA = emB;
      int tn = (t + 2 < len) ? t + 2 : len - 1;
      emB = emb[(size_t)tn * Cq + cl];
      float m = ffl(alpha);                      // uniform shift (lane-0 alpha, near max)
      float e = exp2f((alpha - m) * L2E);        // lanes >= C: exp(-huge)=0
      float s0 = 0.f, s1 = 0.f, s2 = 0.f, s3 = 0.f;
#pragma unroll
      for (int p = 0; p < Cq; p += 4) {
        s0 += frl(e, p) * Ecol[p];
        if (p + 1 < Cq) s1 += frl(e, p + 1) * Ecol[p + 1];
        if (p + 2 < Cq) s2 += frl(e, p + 2) * Ecol[p + 2];
        if (p + 3 < Cq) s3 += frl(e, p + 3) * Ecol[p + 3];
      }
      float ssum = (s0 + s1) + (s2 + s3);
      alpha = m + log2f(ssum) * LN2 + em_cur;
    }
    float xv = (lane < Cq) ? alpha + endv[cl] : -3.0e38f;
    float mm = xv;
#pragma unroll
    for (int off = 32; off; off >>= 1) mm = fmaxf(mm, __shfl_xor(mm, off));
    float es = exp2f((xv - mm) * L2E);
#pragma unroll
    for (int off = 32; off; off >>= 1) es += __shfl_xor(es, off);
    if (lane == 0) s_logZ = mm + log2f(es) * LN2;
  } else if (wid == 1) {
    // ---- viterbi value recursion (max only; bp recomputed later in parallel) ----
    float Tcol[Cq];
#pragma unroll
    for (int p = 0; p < Cq; ++p) Tcol[p] = trans[p * Cq + cl];
    float v = (lane < Cq) ? (startv[cl] + emb[cl]) : -3.0e38f;
    if (lane < Cq) vhist[((size_t)b * Sq) * VST + cl] = v;
    float emA = emb[Cq + cl];
    float emB = emb[(size_t)(2 < len ? 2 : len - 1) * Cq + cl];
    for (int t = 1; t < len; ++t) {
      float em_cur = emA; emA = emB;
      int tn = (t + 2 < len) ? t + 2 : len - 1;
      emB = emb[(size_t)tn * Cq + cl];
      float best = -3.0e38f;
#pragma unroll
      for (int p = 0; p < Cq; ++p) best = fmaxf(best, frl(v, p) + Tcol[p]);
      v = (lane < Cq) ? best + em_cur : -3.0e38f;
      if (lane < Cq) vhist[((size_t)b * Sq + t) * VST + cl] = v;
    }
    float xv = (lane < Cq) ? v + endv[cl] : -3.0e38f;
    int idx = (lane < Cq) ? lane : 1000;
#pragma unroll
    for (int off = 32; off; off >>= 1) {      // argmax, first-index tie-break
      float xo = __shfl_xor(xv, off); int io = __shfl_xor(idx, off);
      if (xo > xv || (xo == xv && io < idx)) { xv = xo; idx = io; }
    }
    if (lane == 0) { lastp[b] = idx; lenp[b] = len; }
  } else if (wid == 2) {
    // ---- gold path score (parallel over t) ----
    const int* lab = labels + (size_t)b * Sq;
    float sc = 0.f;
#pragma unroll
    for (int k = 0; k < 8; ++k) {
      int t = 1 + lane + k * 64;
      if (t < len) {
        int lp = lab[t - 1], lt = lab[t];
        sc += trans[lp * Cq + lt] + emb[(size_t)t * Cq + lt];
      }
    }
#pragma unroll
    for (int off = 32; off; off >>= 1) sc += __shfl_xor(sc, off);
    if (lane == 0) {
      int l0 = lab[0], lf = lab[len - 1];
      s_score = sc + startv[l0] + emb[l0] + endv[lf];
    }
  }
  __syncthreads();
  if (tid == 0) llp[b] = s_score - s_logZ;
}

// ---------------- Kernel 3: recompute all backpointers in parallel ----------------
__global__ __launch_bounds__(256) void crf_bp_kernel(
    const float* __restrict__ vhist, const float* __restrict__ trans,
    const int* __restrict__ lenp, unsigned char* __restrict__ bp)
{
  int b = blockIdx.x >> 2, chunk = blockIdx.x & 3;
  int wid = threadIdx.x >> 6, lane = threadIdx.x & 63;
  int cl = lane < Cq ? lane : Cq - 1;
  int len = lenp[b];
  float Tcol[Cq];
#pragma unroll
  for (int p = 0; p < Cq; ++p) Tcol[p] = trans[p * Cq + cl];
  int tend = 1 + (chunk + 1) * 128; if (tend > len) tend = len;
  int rl9 = lane < VST ? lane : VST - 1;
  for (int t = 1 + chunk * 128 + wid; t < tend; t += 4) {
    float vr = vhist[((size_t)b * Sq + (t - 1)) * VST + rl9];
    float best = -3.0e38f; int bi = 0;
#pragma unroll
    for (int p = 0; p < Cq; ++p) {        // ascending + strict '>' => first-index tie-break
      float cand = frl(vr, p) + Tcol[p];
      if (cand > best) { best = cand; bi = p; }
    }
    if (lane < Cq) bp[((size_t)b * VST + cl) * Sq + t] = (unsigned char)bi;
  }
}

// ---------------- Kernel 4: register-resident backtrack + tag output ----------------
__global__ __launch_bounds__(64) void crf_back_kernel(
    const unsigned char* __restrict__ bp, const int* __restrict__ lenp,
    const int* __restrict__ lastp, float* __restrict__ outp)
{
  int b = blockIdx.x, lane = threadIdx.x;
  int len = __builtin_amdgcn_readfirstlane(lenp[b]);
  int tag = __builtin_amdgcn_readfirstlane(lastp[b]);
  int row = lane < VST ? lane : VST - 1;
  const uint4* src = (const uint4*)(bp + ((size_t)b * VST + row) * Sq);
  unsigned r[128];                         // lane c holds bp[b][c][t], 4 t's per VGPR
#pragma unroll
  for (int k = 0; k < 32; ++k) {
    uint4 q = src[k];
    r[4 * k] = q.x; r[4 * k + 1] = q.y; r[4 * k + 2] = q.z; r[4 * k + 3] = q.w;
  }
  unsigned vt[8];
#pragma unroll
  for (int j = 0; j < 8; ++j) vt[j] = 0u;
  // tag is wave-uniform; (t&63) is a compile-time constant in the unrolled
  // loop -> per-lane select replaces v_writelane (builtin absent in this clang)
  vt[7] = (lane == 63) ? (unsigned)tag : vt[7];
#pragma unroll
  for (int t = 510; t >= 0; --t) {         // uniform chain: readlane with SGPR tag
    int word = __builtin_amdgcn_readlane((int)r[(t + 1) >> 2], tag);
    int nt = (word >> (((t + 1) & 3) * 8)) & 0xff;
    tag = (t + 1 < len) ? nt : tag;
    vt[t >> 6] = (lane == (t & 63)) ? (unsigned)tag : vt[t >> 6];
  }
#pragma unroll
  for (int j = 0; j < 8; ++j) {
    int t = j * 64 + lane;
    float o = (t < len) ? (float)(int)vt[j] : 36.0f;   // PAD_ID = 36
    outp[(size_t)b * Sq + t] = o;
  }
}

// ---------------- Kernel 5: reduce ll partials ----------------
__global__ __launch_bounds__(64) void ll_reduce_kernel(
    const float* __restrict__ llp, float* __restrict__ outp)
{
  int lane = threadIdx.x;
  float s = llp[lane] + llp[lane + 64];
#pragma unroll
  for (int off = 32; off; off >>= 1) s += __shfl_xor(s, off);
  if (lane == 0) outp[0] = s;
}

extern "C" void kernel_launch(void* const* d_in, const int* in_sizes, int n_in,
                              void* d_out, int out_size, void* d_ws, size_t ws_size,
                              hipStream_t stream)
{
  const float* x      = (const float*)d_in[0];
  const float* W      = (const float*)d_in[1];
  const float* bias   = (const float*)d_in[2];
  const float* startv = (const float*)d_in[3];
  const float* endv   = (const float*)d_in[4];
  const float* trans  = (const float*)d_in[5];
  const int*   labels = (const int*)d_in[6];
  const unsigned char* maskb = (const unsigned char*)d_in[7];
  float* out = (float*)d_out;

  char* ws = (char*)d_ws;
  float* em            = (float*)(ws);                  // 65536*37*4       = 9,699,328
  float* vhist         = (float*)(ws + 9699328);        // 128*512*40*4     = 10,485,760
  unsigned char* bpbuf = (unsigned char*)(ws + 20185088); // 128*40*512     = 2,621,440
  float* llp           = (float*)(ws + 22806528);       // 128*4
  int*   lenp          = (int*)(ws + 22807040);         // 128*4
  int*   lastp         = (int*)(ws + 22807552);         // 128*4  (total ~21.8 MB)

  emis_kernel<<<256, 256, 0, stream>>>(x, W, bias, em);
  crf_serial_kernel<<<128, 256, 0, stream>>>(em, startv, endv, trans, labels, maskb,
                                             vhist, llp, lenp, lastp);
  crf_bp_kernel<<<512, 256, 0, stream>>>(vhist, trans, lenp, bpbuf);
  crf_back_kernel<<<128, 64, 0, stream>>>(bpbuf, lenp, lastp, out + 1);
  ll_reduce_kernel<<<1, 64, 0, stream>>>(llp, out);
}

// Round 3
// 363.164 us; speedup vs baseline: 1.2714x; 1.2714x over previous
//
#include <hip/hip_runtime.h>

#define Bq 128
#define Sq 512
#define Cq 37
#define Dq 768
#define VST 40   // vhist row stride in floats; bp row stride uses Sq

static __device__ __forceinline__ float frl(float v, int lane) {
  return __int_as_float(__builtin_amdgcn_readlane(__float_as_int(v), lane));
}
static __device__ __forceinline__ float ffl(float v) {
  return __int_as_float(__builtin_amdgcn_readfirstlane(__float_as_int(v)));
}

// ---------------- Kernel 0: transpose W -> Wt[c][d] (so emis W reads are s_load-able) ----
__global__ __launch_bounds__(256) void prep_kernel(
    const float* __restrict__ W, float* __restrict__ Wt)
{
  for (int i = blockIdx.x * 256 + threadIdx.x; i < Dq * Cq; i += gridDim.x * 256) {
    int d = i / Cq, c = i % Cq;
    Wt[(size_t)c * Dq + d] = W[i];
  }
}

// ---------------- Kernel 1: emissions = x @ W + b ----------------
// block = 256 thr = 4 waves over 64 tokens; wave w owns classes c == w (mod 4).
// x tile staged in LDS (coalesced); W read via wave-uniform s_load from Wt.
__global__ __launch_bounds__(256) void emis_kernel(
    const float* __restrict__ x, const float* __restrict__ Wt,
    const float* __restrict__ bias, float* __restrict__ em)
{
  __shared__ float tile[64 * 36];                       // 64 tokens x 32 d, stride 36 (16B-aligned, bank-min)
  int tid = threadIdx.x;
  int lane = tid & 63;
  int wq = __builtin_amdgcn_readfirstlane(tid >> 6);    // wave id 0..3, provably uniform
  int tok0 = blockIdx.x * 64;
  float acc[10];
#pragma unroll
  for (int k = 0; k < 10; ++k) acc[k] = 0.f;

  for (int d0 = 0; d0 < Dq; d0 += 32) {
    __syncthreads();                                    // protect prior reads
#pragma unroll
    for (int l = 0; l < 2; ++l) {                       // 64x32 floats, coalesced 128B per 8 lanes
      int idx = l * 256 + tid;
      int r = idx >> 3, c4 = idx & 7;
      float4 v = *(const float4*)(x + (size_t)(tok0 + r) * Dq + d0 + c4 * 4);
      *(float4*)(tile + r * 36 + c4 * 4) = v;
    }
    __syncthreads();
    float4 xr[8];
#pragma unroll
    for (int q = 0; q < 8; ++q) xr[q] = *(const float4*)(tile + lane * 36 + q * 4);
#pragma unroll
    for (int k = 0; k < 10; ++k) {
      int cc = wq + 4 * k;                              // uniform per wave
      if (cc < Cq) {
        const float* wr = Wt + (size_t)cc * Dq + d0;    // uniform address -> s_load
        float a = acc[k];
#pragma unroll
        for (int q = 0; q < 8; ++q) {
          a += xr[q].x * wr[q * 4 + 0];
          a += xr[q].y * wr[q * 4 + 1];
          a += xr[q].z * wr[q * 4 + 2];
          a += xr[q].w * wr[q * 4 + 3];
        }
        acc[k] = a;
      }
    }
  }
#pragma unroll
  for (int k = 0; k < 10; ++k) {
    int cc = wq + 4 * k;
    if (cc < Cq) em[(size_t)(tok0 + lane) * Cq + cc] = acc[k] + bias[cc];
  }
}

// ---------------- Kernel 2: serial CRF (forward LSE, viterbi values, gold score) ----------------
__global__ __launch_bounds__(256) void crf_serial_kernel(
    const float* __restrict__ em, const float* __restrict__ startv,
    const float* __restrict__ endv, const float* __restrict__ trans,
    const int* __restrict__ labels, const unsigned char* __restrict__ maskb,
    float* __restrict__ vhist, float* __restrict__ llp,
    int* __restrict__ lenp, int* __restrict__ lastp)
{
  int b = blockIdx.x;
  int tid = threadIdx.x, wid = tid >> 6, lane = tid & 63;
  int cl = lane < Cq ? lane : Cq - 1;
  __shared__ float s_score, s_logZ;

  // mask element-size detect: bool(u8) layout has byte1==1 (len>=16), int32 has 0
  int esz4 = (maskb[1] == 0) ? 1 : 0;
  int len = 0;
#pragma unroll
  for (int k = 0; k < 8; ++k) {
    size_t t = (size_t)lane + (size_t)k * 64;
    unsigned char mb = esz4 ? maskb[((size_t)b * Sq + t) * 4] : maskb[(size_t)b * Sq + t];
    len += (mb != 0);
  }
#pragma unroll
  for (int off = 32; off; off >>= 1) len += __shfl_xor(len, off);

  const float* emb = em + (size_t)b * Sq * Cq;
  const float L2E = 1.4426950408889634f, LN2 = 0.6931471805599453f;

  if (wid == 0) {
    // ---- forward algorithm (log partition) ----
    float Ecol[Cq];
#pragma unroll
    for (int p = 0; p < Cq; ++p) Ecol[p] = expf(trans[p * Cq + cl]);
    float alpha = (lane < Cq) ? (startv[cl] + emb[cl]) : -3.0e38f;
    float emA = emb[Cq + cl];
    float emB = emb[(size_t)(2 < len ? 2 : len - 1) * Cq + cl];
    for (int t = 1; t < len; ++t) {
      float em_cur = emA; emA = emB;
      int tn = (t + 2 < len) ? t + 2 : len - 1;
      emB = emb[(size_t)tn * Cq + cl];
      float m = ffl(alpha);                      // uniform shift (lane-0 alpha, near max)
      float e = exp2f((alpha - m) * L2E);        // lanes >= C: exp(-huge)=0
      float s0 = 0.f, s1 = 0.f, s2 = 0.f, s3 = 0.f;
#pragma unroll
      for (int p = 0; p < Cq; p += 4) {
        s0 += frl(e, p) * Ecol[p];
        if (p + 1 < Cq) s1 += frl(e, p + 1) * Ecol[p + 1];
        if (p + 2 < Cq) s2 += frl(e, p + 2) * Ecol[p + 2];
        if (p + 3 < Cq) s3 += frl(e, p + 3) * Ecol[p + 3];
      }
      float ssum = (s0 + s1) + (s2 + s3);
      alpha = m + log2f(ssum) * LN2 + em_cur;
    }
    float xv = (lane < Cq) ? alpha + endv[cl] : -3.0e38f;
    float mm = xv;
#pragma unroll
    for (int off = 32; off; off >>= 1) mm = fmaxf(mm, __shfl_xor(mm, off));
    float es = exp2f((xv - mm) * L2E);
#pragma unroll
    for (int off = 32; off; off >>= 1) es += __shfl_xor(es, off);
    if (lane == 0) s_logZ = mm + log2f(es) * LN2;
  } else if (wid == 1) {
    // ---- viterbi value recursion (max only; bp recomputed later in parallel) ----
    float Tcol[Cq];
#pragma unroll
    for (int p = 0; p < Cq; ++p) Tcol[p] = trans[p * Cq + cl];
    float v = (lane < Cq) ? (startv[cl] + emb[cl]) : -3.0e38f;
    if (lane < Cq) vhist[((size_t)b * Sq) * VST + cl] = v;
    float emA = emb[Cq + cl];
    float emB = emb[(size_t)(2 < len ? 2 : len - 1) * Cq + cl];
    for (int t = 1; t < len; ++t) {
      float em_cur = emA; emA = emB;
      int tn = (t + 2 < len) ? t + 2 : len - 1;
      emB = emb[(size_t)tn * Cq + cl];
      float b0 = -3.0e38f, b1 = -3.0e38f, b2 = -3.0e38f, b3 = -3.0e38f;
#pragma unroll
      for (int p = 0; p < Cq; p += 4) {        // 4 independent max chains
        b0 = fmaxf(b0, frl(v, p) + Tcol[p]);
        if (p + 1 < Cq) b1 = fmaxf(b1, frl(v, p + 1) + Tcol[p + 1]);
        if (p + 2 < Cq) b2 = fmaxf(b2, frl(v, p + 2) + Tcol[p + 2]);
        if (p + 3 < Cq) b3 = fmaxf(b3, frl(v, p + 3) + Tcol[p + 3]);
      }
      float best = fmaxf(fmaxf(b0, b1), fmaxf(b2, b3));
      v = (lane < Cq) ? best + em_cur : -3.0e38f;
      if (lane < Cq) vhist[((size_t)b * Sq + t) * VST + cl] = v;
    }
    float xv = (lane < Cq) ? v + endv[cl] : -3.0e38f;
    int idx = (lane < Cq) ? lane : 1000;
#pragma unroll
    for (int off = 32; off; off >>= 1) {      // argmax, first-index tie-break
      float xo = __shfl_xor(xv, off); int io = __shfl_xor(idx, off);
      if (xo > xv || (xo == xv && io < idx)) { xv = xo; idx = io; }
    }
    if (lane == 0) { lastp[b] = idx; lenp[b] = len; }
  } else if (wid == 2) {
    // ---- gold path score (parallel over t) ----
    const int* lab = labels + (size_t)b * Sq;
    float sc = 0.f;
#pragma unroll
    for (int k = 0; k < 8; ++k) {
      int t = 1 + lane + k * 64;
      if (t < len) {
        int lp = lab[t - 1], lt = lab[t];
        sc += trans[lp * Cq + lt] + emb[(size_t)t * Cq + lt];
      }
    }
#pragma unroll
    for (int off = 32; off; off >>= 1) sc += __shfl_xor(sc, off);
    if (lane == 0) {
      int l0 = lab[0], lf = lab[len - 1];
      s_score = sc + startv[l0] + emb[l0] + endv[lf];
    }
  }
  __syncthreads();
  if (tid == 0) llp[b] = s_score - s_logZ;
}

// ---------------- Kernel 3: recompute all backpointers in parallel ----------------
__global__ __launch_bounds__(256) void crf_bp_kernel(
    const float* __restrict__ vhist, const float* __restrict__ trans,
    const int* __restrict__ lenp, unsigned char* __restrict__ bp)
{
  int b = blockIdx.x >> 2, chunk = blockIdx.x & 3;
  int wid = threadIdx.x >> 6, lane = threadIdx.x & 63;
  int cl = lane < Cq ? lane : Cq - 1;
  int len = lenp[b];
  float Tcol[Cq];
#pragma unroll
  for (int p = 0; p < Cq; ++p) Tcol[p] = trans[p * Cq + cl];
  int tend = 1 + (chunk + 1) * 128; if (tend > len) tend = len;
  int rl9 = lane < VST ? lane : VST - 1;
  for (int t = 1 + chunk * 128 + wid; t < tend; t += 4) {
    float vr = vhist[((size_t)b * Sq + (t - 1)) * VST + rl9];
    float best = -3.0e38f; int bi = 0;
#pragma unroll
    for (int p = 0; p < Cq; ++p) {        // ascending + strict '>' => first-index tie-break
      float cand = frl(vr, p) + Tcol[p];
      if (cand > best) { best = cand; bi = p; }
    }
    if (lane < Cq) bp[((size_t)b * VST + cl) * Sq + t] = (unsigned char)bi;
  }
}

// ---------------- Kernel 4: register-resident backtrack + tag output ----------------
__global__ __launch_bounds__(64) void crf_back_kernel(
    const unsigned char* __restrict__ bp, const int* __restrict__ lenp,
    const int* __restrict__ lastp, float* __restrict__ outp)
{
  int b = blockIdx.x, lane = threadIdx.x;
  int len = __builtin_amdgcn_readfirstlane(lenp[b]);
  int tag = __builtin_amdgcn_readfirstlane(lastp[b]);
  int row = lane < VST ? lane : VST - 1;
  const uint4* src = (const uint4*)(bp + ((size_t)b * VST + row) * Sq);
  unsigned r[128];                         // lane c holds bp[b][c][t], 4 t's per VGPR
#pragma unroll
  for (int k = 0; k < 32; ++k) {
    uint4 q = src[k];
    r[4 * k] = q.x; r[4 * k + 1] = q.y; r[4 * k + 2] = q.z; r[4 * k + 3] = q.w;
  }
  unsigned vt[8];
#pragma unroll
  for (int j = 0; j < 8; ++j) vt[j] = 0u;
  vt[7] = (lane == 63) ? (unsigned)tag : vt[7];
#pragma unroll
  for (int t = 510; t >= 0; --t) {         // uniform chain: readlane with SGPR tag
    int word = __builtin_amdgcn_readlane((int)r[(t + 1) >> 2], tag);
    int nt = (word >> (((t + 1) & 3) * 8)) & 0xff;
    tag = (t + 1 < len) ? nt : tag;
    vt[t >> 6] = (lane == (t & 63)) ? (unsigned)tag : vt[t >> 6];
  }
#pragma unroll
  for (int j = 0; j < 8; ++j) {
    int t = j * 64 + lane;
    float o = (t < len) ? (float)(int)vt[j] : 36.0f;   // PAD_ID = 36
    outp[(size_t)b * Sq + t] = o;
  }
}

// ---------------- Kernel 5: reduce ll partials ----------------
__global__ __launch_bounds__(64) void ll_reduce_kernel(
    const float* __restrict__ llp, float* __restrict__ outp)
{
  int lane = threadIdx.x;
  float s = llp[lane] + llp[lane + 64];
#pragma unroll
  for (int off = 32; off; off >>= 1) s += __shfl_xor(s, off);
  if (lane == 0) outp[0] = s;
}

extern "C" void kernel_launch(void* const* d_in, const int* in_sizes, int n_in,
                              void* d_out, int out_size, void* d_ws, size_t ws_size,
                              hipStream_t stream)
{
  const float* x      = (const float*)d_in[0];
  const float* W      = (const float*)d_in[1];
  const float* bias   = (const float*)d_in[2];
  const float* startv = (const float*)d_in[3];
  const float* endv   = (const float*)d_in[4];
  const float* trans  = (const float*)d_in[5];
  const int*   labels = (const int*)d_in[6];
  const unsigned char* maskb = (const unsigned char*)d_in[7];
  float* out = (float*)d_out;

  char* ws = (char*)d_ws;
  float* em            = (float*)(ws);                  // 65536*37*4       = 9,699,328
  float* vhist         = (float*)(ws + 9699328);        // 128*512*40*4     = 10,485,760
  unsigned char* bpbuf = (unsigned char*)(ws + 20185088); // 128*40*512     = 2,621,440
  float* llp           = (float*)(ws + 22806528);       // 128*4
  int*   lenp          = (int*)(ws + 22807040);         // 128*4
  int*   lastp         = (int*)(ws + 22807552);         // 128*4
  float* Wt            = (float*)(ws + 22808064);       // 37*768*4 = 113,664  (total ~21.9 MB)

  prep_kernel<<<28, 256, 0, stream>>>(W, Wt);
  emis_kernel<<<1024, 256, 0, stream>>>(x, Wt, bias, em);
  crf_serial_kernel<<<128, 256, 0, stream>>>(em, startv, endv, trans, labels, maskb,
                                             vhist, llp, lenp, lastp);
  crf_bp_kernel<<<512, 256, 0, stream>>>(vhist, trans, lenp, bpbuf);
  crf_back_kernel<<<128, 64, 0, stream>>>(bpbuf, lenp, lastp, out + 1);
  ll_reduce_kernel<<<1, 64, 0, stream>>>(llp, out);
}